// Round 7
// baseline (477.409 us; speedup 1.0000x reference)
//
#include <hip/hip_runtime.h>
#include <math.h>

// CRF layer: B=2048 sequences, T=512 max steps, C=32 tags.
// out = [ tags as float (B*T) | loss (1) ], total 1048577 floats.
#define BB 2048
#define TT 512
#define CC 32

#if __has_builtin(__builtin_amdgcn_exp2f)
#define EXP2F __builtin_amdgcn_exp2f
#else
#define EXP2F exp2f
#endif
#if __has_builtin(__builtin_amdgcn_logf)
#define LOG2F __builtin_amdgcn_logf   // v_log_f32 computes log2
#else
#define LOG2F log2f
#endif

#define LOG2E 1.4426950408889634f
#define LN2   0.6931471805599453f

__global__ void zero_loss_kernel(float* __restrict__ out) {
  if (threadIdx.x == 0) out[(size_t)BB * TT] = 0.0f;
}

// Setup: counting-sort by length (descending rank r), then scatter so that
// position p holds rank (p%8)*256 + p/8.  Any CU that receives 8 blocks —
// whether round-robin (p, p+256, ...) or chunked (8p..8p+7) — gets one
// block from each length-octile, so per-CU makespans are balanced without
// pairing.  One block, TT=512 threads.
__global__ void schedule_kernel(const int* __restrict__ seqlen,
                                int* __restrict__ perm,
                                float* __restrict__ out) {
  __shared__ int s[TT];
  __shared__ int off[TT];
  const int tid = threadIdx.x;
  if (tid == 0) out[(size_t)BB * TT] = 0.0f;
  s[tid] = 0;
  __syncthreads();
  for (int b = tid; b < BB; b += TT) atomicAdd(&s[seqlen[b] - 1], 1);
  __syncthreads();
  for (int d = 1; d < TT; d <<= 1) {       // inclusive suffix scan
    int v = s[tid] + ((tid + d < TT) ? s[tid + d] : 0);
    __syncthreads();
    s[tid] = v;
    __syncthreads();
  }
  off[tid] = (tid + 1 < TT) ? s[tid + 1] : 0;  // exclusive suffix sum
  __syncthreads();
  for (int b = tid; b < BB; b += TT) {
    int r = atomicAdd(&off[seqlen[b] - 1], 1);   // descending length rank
    int p = (r & 7) * 256 + (r >> 3);            // octile scatter (bijection)
    perm[p] = b;
  }
}

// DPP row rotate-right by K: lane i reads lane (i-K)&15 within its 16-row.
#define ROR(dst, src, K)                                                     \
  dst = __int_as_float(__builtin_amdgcn_update_dpp(                          \
      0, __float_as_int(src), 0x120 | (K), 0xF, 0xF, false));

// ---- cross-lane xor16 / xor32 without DS latency (gfx950 permlane swaps) --
__device__ __forceinline__ float xor16f(float x, int lane) {
#if __has_builtin(__builtin_amdgcn_permlane16_swap)
  auto r = __builtin_amdgcn_permlane16_swap(__float_as_uint(x),
                                            __float_as_uint(x), false, false);
  return __uint_as_float((lane & 16) ? r[0] : r[1]);
#else
  return __int_as_float(
      __builtin_amdgcn_ds_swizzle(__float_as_int(x), 0x401F));
#endif
}
__device__ __forceinline__ float xor32f(float x, int lane) {
#if __has_builtin(__builtin_amdgcn_permlane32_swap)
  auto r = __builtin_amdgcn_permlane32_swap(__float_as_uint(x),
                                            __float_as_uint(x), false, false);
  return __uint_as_float((lane & 32) ? r[0] : r[1]);
#else
  return __shfl_xor(x, 32);
#endif
}
__device__ __forceinline__ int xor32i(int x, int lane) {
#if __has_builtin(__builtin_amdgcn_permlane32_swap)
  auto r = __builtin_amdgcn_permlane32_swap((unsigned)x, (unsigned)x,
                                            false, false);
  return (int)((lane & 32) ? r[0] : r[1]);
#else
  return __shfl_xor(x, 32);
#endif
}

// One sequence per block (grid 2048 -> 8 blocks/CU, 4 waves/SIMD: fills the
// idle issue slots R6 left at 2 waves/SIMD).  LDS cut to ~17 KB: backtrace
// ragged head needs only the LAST <=3 backpointer rows -> cyclic 4-row
// buffer; gp_s 4-step composed maps carry the rest.
//   wave 0 (V): Viterbi, register alphas (DPP + permlane).  av recurrence
//       decoupled from tie-break (av = logit + max(best,ov)); index path
//       off-chain.  Main chunks fully unguarded (compose at static s=3/7).
//   wave 1 (F): forward in scaled linear domain (renorm at static s=3/7).
__global__ __launch_bounds__(128, 4) void crf_kernel(
    const float* __restrict__ logits,     // [B, T, C]
    const int*   __restrict__ seqlen,     // [B]
    const int*   __restrict__ labels,     // [B, T]
    const float* __restrict__ trans,      // [C, C]  trans[p*C + c]
    float*       __restrict__ out,        // [B*T + 1]
    const int*   __restrict__ perm)       // [B] scattered order, or nullptr
{
  __shared__ __align__(16) unsigned char bp_s[4 * CC];    // cyclic, 128 B
  __shared__ __align__(16) unsigned gp_s[(TT / 4) * CC];  // 16,384 B
  __shared__ unsigned char tag_s[TT];

  const int lane = threadIdx.x & 63;
  const int wv   = threadIdx.x >> 6;     // 0 = viterbi, 1 = forward
  const int b    = perm ? perm[blockIdx.x] : blockIdx.x;

  const int len = seqlen[b];
  const float* lg = logits + (size_t)b * TT * CC;
  const size_t bT = (size_t)b * TT;
  const float* lgc = lg + (lane & 31);

  const int i  = lane & 15;
  const int c  = lane & 31;              // column; lanes 32-63 mirror 0-31
  const int r  = (lane >> 4) & 1;        // row of own column
  const int pr = (lane < 32) ? r : 1 - r;  // prev-row group this lane reduces

  if (wv == 0) {
    // ================= Viterbi wave (register alphas, DPP) =================
    float tr2[16];
    int   pidx[16];
#pragma unroll
    for (int kk = 0; kk < 16; ++kk) {
      int p = pr * 16 + ((i - kk) & 15);
      pidx[kk] = p;
      tr2[kk] = trans[p * CC + c];
    }

    float av = lg[c];                    // alpha, duplicated across halves

    // returns bpi (identical on both lane halves); av chain decoupled
    auto vstep = [&](int t, float logit_c) -> int {
      float base = (lane < 32) ? av : xor16f(av, lane);
      float S[16];
      float x;
      S[0] = base + tr2[0];
      ROR(x, base, 1);  S[1]  = x + tr2[1];
      ROR(x, base, 2);  S[2]  = x + tr2[2];
      ROR(x, base, 3);  S[3]  = x + tr2[3];
      ROR(x, base, 4);  S[4]  = x + tr2[4];
      ROR(x, base, 5);  S[5]  = x + tr2[5];
      ROR(x, base, 6);  S[6]  = x + tr2[6];
      ROR(x, base, 7);  S[7]  = x + tr2[7];
      ROR(x, base, 8);  S[8]  = x + tr2[8];
      ROR(x, base, 9);  S[9]  = x + tr2[9];
      ROR(x, base, 10); S[10] = x + tr2[10];
      ROR(x, base, 11); S[11] = x + tr2[11];
      ROR(x, base, 12); S[12] = x + tr2[12];
      ROR(x, base, 13); S[13] = x + tr2[13];
      ROR(x, base, 14); S[14] = x + tr2[14];
      ROR(x, base, 15); S[15] = x + tr2[15];

      float a = fmaxf(fmaxf(S[0], S[1]), S[2]);
      float bq = fmaxf(fmaxf(S[3], S[4]), S[5]);
      float cq = fmaxf(fmaxf(S[6], S[7]), S[8]);
      float dq = fmaxf(fmaxf(S[9], S[10]), S[11]);
      float eq = fmaxf(fmaxf(S[12], S[13]), S[14]);
      float best = fmaxf(fmaxf(fmaxf(a, bq), fmaxf(cq, dq)),
                         fmaxf(eq, S[15]));

      // value recurrence: does NOT wait for the tie-break index
      float ov = xor32f(best, lane);
      av = logit_c + fmaxf(best, ov);

      // tie-break (min prev-tag among maxima) — off the serial chain
      int t8[16];
#pragma unroll
      for (int kk = 0; kk < 16; ++kk)
        t8[kk] = (S[kk] == best) ? pidx[kk] : 63;
      int ma = min(min(t8[0], t8[1]), t8[2]);
      int mb = min(min(t8[3], t8[4]), t8[5]);
      int mc = min(min(t8[6], t8[7]), t8[8]);
      int md = min(min(t8[9], t8[10]), t8[11]);
      int me = min(min(t8[12], t8[13]), t8[14]);
      int bi = min(min(min(ma, mb), min(mc, md)), min(me, t8[15]));

      int oi = xor32i(bi, lane);
      bool take = (ov > best) || (ov == best && oi < bi);
      int bpi = take ? oi : bi;

      // cyclic 4-row backpointer (head-of-backtrace only); both halves
      // write the same value to the same address (free 2-way, no exec mask)
      bp_s[((t - 1) & 3) * CC + c] = (unsigned char)bpi;
      return bpi;
    };

    auto compose = [&](int tt, int b3, int b2, int b1, int b0) {
      // m1=bp[tt], m2=bp[tt-1]∘m1, m3=bp[tt-2]∘m2, m4=bp[tt-3]∘m3
      int m2 = __builtin_amdgcn_ds_bpermute(b3 << 2, b2);
      int m3 = __builtin_amdgcn_ds_bpermute(m2 << 2, b1);
      int m4 = __builtin_amdgcn_ds_bpermute(m3 << 2, b0);
      unsigned packed = (unsigned)b3 | ((unsigned)m2 << 8) |
                        ((unsigned)m3 << 16) | ((unsigned)m4 << 24);
      gp_s[((tt >> 2) - 1) * CC + c] = packed;
    };

    float Abk[8], Bbk[8];
    auto loadC = [&](float (&bk)[8], int t0) {   // clamped, off-chain
#pragma unroll
      for (int s = 0; s < 8; ++s) {
        int tt = t0 + s; tt = tt < len ? tt : len - 1;
        bk[s] = lgc[tt * CC];
      }
    };
    // t0 ≡ 1 (mod 8): group ends land statically at s=3 and s=7.
    auto runFull = [&](float (&bk)[8], int t0) {
      int b0 = vstep(t0 + 0, bk[0]);
      int b1 = vstep(t0 + 1, bk[1]);
      int b2 = vstep(t0 + 2, bk[2]);
      int b3 = vstep(t0 + 3, bk[3]);
      compose(t0 + 3, b3, b2, b1, b0);
      int b4 = vstep(t0 + 4, bk[4]);
      int b5 = vstep(t0 + 5, bk[5]);
      int b6 = vstep(t0 + 6, bk[6]);
      int b7 = vstep(t0 + 7, bk[7]);
      compose(t0 + 7, b7, b6, b5, b4);
    };
    auto runGuard = [&](float (&bk)[8], int t0) {
      int h1 = 0, h2 = 0, h3 = 0;
#pragma unroll
      for (int s = 0; s < 8; ++s) {
        int tt = t0 + s;
        if (tt < len) {
          int bpi = vstep(tt, bk[s]);
          if ((tt & 3) == 0) compose(tt, bpi, h1, h2, h3);
          h3 = h2; h2 = h1; h1 = bpi;
        }
      }
    };

    loadC(Abk, 1);
    int t0 = 1;
    for (; t0 + 16 <= len; t0 += 16) {
      loadC(Bbk, t0 + 8);
      runFull(Abk, t0);
      loadC(Abk, t0 + 16);
      runFull(Bbk, t0 + 8);
    }
    if (t0 < len) {
      loadC(Bbk, t0 + 8);
      runGuard(Abk, t0);
      if (t0 + 8 < len) runGuard(Bbk, t0 + 8);
    }

    // last tag: argmax over c (first index on ties)
    float v = av; int idx = c;
#pragma unroll
    for (int d = 1; d < 32; d <<= 1) {
      float v2 = __shfl_xor(v, d, 32);
      int   i2 = __shfl_xor(idx, d, 32);
      if (v2 > v || (v2 == v && i2 < idx)) { v = v2; idx = i2; }
    }

    // backtrace: ragged head via cyclic rows (last <=3 steps), then 4-jumps
    if (lane == 0) {
      int tag = idx;
      int t = len - 1;
      tag_s[t] = (unsigned char)tag;
      while (t > 0 && (t & 3) != 0) {
        tag = bp_s[((t - 1) & 3) * CC + tag];
        --t;
        tag_s[t] = (unsigned char)tag;
      }
      while (t >= 4) {
        unsigned u = gp_s[((t >> 2) - 1) * CC + tag];
        tag_s[t - 1] = (unsigned char)(u & 255);
        tag_s[t - 2] = (unsigned char)((u >> 8) & 255);
        tag_s[t - 3] = (unsigned char)((u >> 16) & 255);
        tag = (int)(u >> 24);
        tag_s[t - 4] = (unsigned char)tag;
        t -= 4;
      }
    }

    // coalesced tag store (+ zero padding)
#pragma unroll
    for (int j = 0; j < 8; ++j) {
      int tt = lane + 64 * j;
      float val = (tt < len) ? (float)tag_s[tt] : 0.0f;
      out[bT + tt] = val;
    }

  } else {
    // ================= Forward wave (scaled linear domain) =================
    const int* lab = labels + (size_t)b * TT;
    float E[16];
#pragma unroll
    for (int kk = 0; kk < 16; ++kk) {
      int p = pr * 16 + ((i - kk) & 15);
      E[kk] = EXP2F(trans[p * CC + c] * LOG2E);
    }

    float P   = EXP2F(lg[c] * LOG2E);    // scaled linear alpha for column c
    float Acc = 0.0f;                    // accumulated log2 scale (uniform)

    auto fstep = [&](float raw_logit) {
      float el = EXP2F(raw_logit * LOG2E);   // off the serial P-chain
      float base = (lane < 32) ? P : xor16f(P, lane);
      float x;
      float a0 = base * E[0];
      ROR(x, base, 1);  float a1 = x * E[1];
      ROR(x, base, 2);  float a2 = x * E[2];
      ROR(x, base, 3);  float a3 = x * E[3];
      ROR(x, base, 4);  a0 = fmaf(x, E[4],  a0);
      ROR(x, base, 5);  a1 = fmaf(x, E[5],  a1);
      ROR(x, base, 6);  a2 = fmaf(x, E[6],  a2);
      ROR(x, base, 7);  a3 = fmaf(x, E[7],  a3);
      ROR(x, base, 8);  a0 = fmaf(x, E[8],  a0);
      ROR(x, base, 9);  a1 = fmaf(x, E[9],  a1);
      ROR(x, base, 10); a2 = fmaf(x, E[10], a2);
      ROR(x, base, 11); a3 = fmaf(x, E[11], a3);
      ROR(x, base, 12); a0 = fmaf(x, E[12], a0);
      ROR(x, base, 13); a1 = fmaf(x, E[13], a1);
      ROR(x, base, 14); a2 = fmaf(x, E[14], a2);
      ROR(x, base, 15); a3 = fmaf(x, E[15], a3);
      float part = (a0 + a1) + (a2 + a3);      // this lane's 16-row partial
      float oth  = xor32f(part, lane);         // other row's partial
      P = el * (part + oth);
    };

    auto renorm = [&]() {
      float m = P, y;
      ROR(y, m, 8); m = fmaxf(m, y);
      ROR(y, m, 4); m = fmaxf(m, y);
      ROR(y, m, 2); m = fmaxf(m, y);
      ROR(y, m, 1); m = fmaxf(m, y);
      m = fmaxf(m, xor16f(m, lane));
      int e = (int)(__float_as_uint(m) >> 23) - 127;  // floor(log2 m)
      P = ldexpf(P, -e);                              // exact scaling
      Acc += (float)e;
    };

    float Abk[8], Bbk[8];
    auto loadC = [&](float (&bk)[8], int t0) {
#pragma unroll
      for (int s = 0; s < 8; ++s) {
        int tt = t0 + s; tt = tt < len ? tt : len - 1;
        bk[s] = lgc[tt * CC];
      }
    };
    auto runFull = [&](float (&bk)[8]) {     // renorm at static s=3, s=7
      fstep(bk[0]); fstep(bk[1]); fstep(bk[2]); fstep(bk[3]); renorm();
      fstep(bk[4]); fstep(bk[5]); fstep(bk[6]); fstep(bk[7]); renorm();
    };
    auto runGuard = [&](float (&bk)[8], int t0) {
#pragma unroll
      for (int s = 0; s < 8; ++s) {
        int tt = t0 + s;
        if (tt < len) {
          fstep(bk[s]);
          if ((tt & 3) == 0) renorm();
        }
      }
    };

    loadC(Abk, 1);
    int t0 = 1;
    for (; t0 + 16 <= len; t0 += 16) {
      loadC(Bbk, t0 + 8);
      runFull(Abk);
      loadC(Abk, t0 + 16);
      runFull(Bbk);
    }
    if (t0 < len) {
      loadC(Bbk, t0 + 8);
      runGuard(Abk, t0);
      if (t0 + 8 < len) runGuard(Bbk, t0 + 8);
    }

    // gold-path score (unary + binary), lane-parallel over t
    float uacc = 0.0f, bacc = 0.0f;
#pragma unroll
    for (int j = 0; j < 8; ++j) {
      int tt = lane + 64 * j;
      if (tt < len) {
        int lt = lab[tt];
        uacc += lg[tt * CC + lt];
        if (tt + 1 < len) {
          int ln = lab[tt + 1];
          bacc += trans[lt * CC + ln];
        }
      }
    }
#pragma unroll
    for (int d = 32; d >= 1; d >>= 1) {
      uacc += __shfl_xor(uacc, d);
      bacc += __shfl_xor(bacc, d);
    }

    // log partition: rotate-fold sum of the 32 scaled alphas + scale
    float ss = P, y2;
    ROR(y2, ss, 8); ss += y2;
    ROR(y2, ss, 4); ss += y2;
    ROR(y2, ss, 2); ss += y2;
    ROR(y2, ss, 1); ss += y2;
    ss += xor16f(ss, lane);
    float log_norm = LN2 * (Acc + LOG2F(ss));

    if (lane == 0) {
      float ll = uacc + bacc - log_norm;
      atomicAdd(out + (size_t)BB * TT, -ll * (1.0f / BB));
    }
  }
}

extern "C" void kernel_launch(void* const* d_in, const int* in_sizes, int n_in,
                              void* d_out, int out_size, void* d_ws, size_t ws_size,
                              hipStream_t stream) {
  const float* logits = (const float*)d_in[0];
  const int*   seqlen = (const int*)d_in[1];
  const int*   labels = (const int*)d_in[2];
  const float* trans  = (const float*)d_in[3];
  float* out = (float*)d_out;

  if (d_ws != nullptr && ws_size >= BB * sizeof(int)) {
    int* perm = (int*)d_ws;
    schedule_kernel<<<1, TT, 0, stream>>>(seqlen, perm, out);
    crf_kernel<<<dim3(BB), dim3(128), 0, stream>>>(
        logits, seqlen, labels, trans, out, perm);
  } else {
    zero_loss_kernel<<<1, 64, 0, stream>>>(out);
    crf_kernel<<<dim3(BB), dim3(128), 0, stream>>>(
        logits, seqlen, labels, trans, out, nullptr);
  }
}

// Round 8
// 354.211 us; speedup vs baseline: 1.3478x; 1.3478x over previous
//
#include <hip/hip_runtime.h>
#include <math.h>

// CRF layer: B=2048 sequences, T=512 max steps, C=32 tags.
// out = [ tags as float (B*T) | loss (1) ], total 1048577 floats.
#define BB 2048
#define TT 512
#define CC 32

#if __has_builtin(__builtin_amdgcn_exp2f)
#define EXP2F __builtin_amdgcn_exp2f
#else
#define EXP2F exp2f
#endif
#if __has_builtin(__builtin_amdgcn_logf)
#define LOG2F __builtin_amdgcn_logf   // v_log_f32 computes log2
#else
#define LOG2F log2f
#endif

#define LOG2E 1.4426950408889634f
#define LN2   0.6931471805599453f

__global__ void zero_loss_kernel(float* __restrict__ out) {
  if (threadIdx.x == 0) out[(size_t)BB * TT] = 0.0f;
}

// Counting-sort sequence indices by length (descending) into perm, zero the
// loss.  Pairing perm[k] with perm[BB-1-k] gives every block ~513 steps of
// work (the R3/R6 structure that measured best).  One block, 512 threads.
__global__ void schedule_kernel(const int* __restrict__ seqlen,
                                int* __restrict__ perm,
                                float* __restrict__ out) {
  __shared__ int s[TT];
  __shared__ int off[TT];
  const int tid = threadIdx.x;
  if (tid == 0) out[(size_t)BB * TT] = 0.0f;
  s[tid] = 0;
  __syncthreads();
  for (int b = tid; b < BB; b += TT) atomicAdd(&s[seqlen[b] - 1], 1);
  __syncthreads();
  for (int d = 1; d < TT; d <<= 1) {       // inclusive suffix scan
    int v = s[tid] + ((tid + d < TT) ? s[tid + d] : 0);
    __syncthreads();
    s[tid] = v;
    __syncthreads();
  }
  off[tid] = (tid + 1 < TT) ? s[tid + 1] : 0;  // exclusive suffix sum
  __syncthreads();
  for (int b = tid; b < BB; b += TT) {
    int pos = atomicAdd(&off[seqlen[b] - 1], 1);
    perm[pos] = b;  // descending length order (ties arbitrary)
  }
}

// DPP row rotate-right by K: lane i reads lane (i-K)&15 within its 16-row.
#define ROR(dst, src, K)                                                     \
  dst = __int_as_float(__builtin_amdgcn_update_dpp(                          \
      0, __float_as_int(src), 0x120 | (K), 0xF, 0xF, false));

// ---- cross-lane xor16 / xor32 without DS latency (gfx950 permlane swaps) --
__device__ __forceinline__ float xor16f(float x, int lane) {
#if __has_builtin(__builtin_amdgcn_permlane16_swap)
  auto r = __builtin_amdgcn_permlane16_swap(__float_as_uint(x),
                                            __float_as_uint(x), false, false);
  return __uint_as_float((lane & 16) ? r[0] : r[1]);
#else
  return __int_as_float(
      __builtin_amdgcn_ds_swizzle(__float_as_int(x), 0x401F));
#endif
}
__device__ __forceinline__ float xor32f(float x, int lane) {
#if __has_builtin(__builtin_amdgcn_permlane32_swap)
  auto r = __builtin_amdgcn_permlane32_swap(__float_as_uint(x),
                                            __float_as_uint(x), false, false);
  return __uint_as_float((lane & 32) ? r[0] : r[1]);
#else
  return __shfl_xor(x, 32);
#endif
}
__device__ __forceinline__ int xor32i(int x, int lane) {
#if __has_builtin(__builtin_amdgcn_permlane32_swap)
  auto r = __builtin_amdgcn_permlane32_swap((unsigned)x, (unsigned)x,
                                            false, false);
  return (int)((lane & 32) ? r[0] : r[1]);
#else
  return __shfl_xor(x, 32);
#endif
}

// Two waves per block; block k processes perm[k] then perm[BB-1-k]
// (length-balanced pair, the proven R6 config: grid 1024, min-waves 2 for
// VGPR headroom).
//   wave 0 (V): Viterbi, register alphas (DPP + permlane), decoupled av
//       chain, cyclic 4-row bp_s.  NEW: the 4-step backpointer-map compose
//       (3 serially-dependent ds_bpermute) is SOFTWARE-PIPELINED: group g's
//       bpermutes are issued one per vstep during group g+1, so their ~120cy
//       DS latency hides under ~200cy of vstep issue (in-order waves stall
//       at first dependent use — inline compose cost ~60-90 cy/step in R6).
//   wave 1 (F): forward pass in scaled linear domain (unchanged from R6).
__global__ __launch_bounds__(128, 2) void crf_kernel(
    const float* __restrict__ logits,     // [B, T, C]
    const int*   __restrict__ seqlen,     // [B]
    const int*   __restrict__ labels,     // [B, T]
    const float* __restrict__ trans,      // [C, C]  trans[p*C + c]
    float*       __restrict__ out,        // [B*T + 1]
    const int*   __restrict__ perm)       // [B] desc-length order, or nullptr
{
  __shared__ __align__(16) unsigned char bp_s[4 * CC];    // cyclic, 128 B
  __shared__ __align__(16) unsigned gp_s[(TT / 4) * CC];  // 16,384 B
  __shared__ unsigned char tag_s[TT];

  const int lane = threadIdx.x & 63;
  const int wv   = threadIdx.x >> 6;     // 0 = viterbi, 1 = forward
  const int k    = blockIdx.x;

  const int bs0 = perm ? perm[k] : k;
  const int bs1 = perm ? perm[BB - 1 - k] : -1;

  const int i  = lane & 15;
  const int c  = lane & 31;              // column; lanes 32-63 mirror 0-31
  const int r  = (lane >> 4) & 1;        // row of own column
  const int pr = (lane < 32) ? r : 1 - r;  // prev-row group this lane reduces

  if (wv == 0) {
    // ================= Viterbi wave (register alphas, DPP) =================
    float tr2[16];
    int   pidx[16];
#pragma unroll
    for (int kk = 0; kk < 16; ++kk) {
      int p = pr * 16 + ((i - kk) & 15);
      pidx[kk] = p;
      tr2[kk] = trans[p * CC + c];
    }

    for (int sq = 0; sq < 2; ++sq) {
      const int b = sq ? bs1 : bs0;
      if (b < 0) break;
      const int len = seqlen[b];
      const float* lg = logits + (size_t)b * TT * CC;
      const size_t bT = (size_t)b * TT;
      const float* lgc = lg + c;

      float av = lg[c];                  // alpha, duplicated across halves

      // pending group awaiting compose: bpi at pend_tt-3..pend_tt
      int p0 = 0, p1 = 0, p2 = 0, p3 = 0, pend_tt = 0;

      auto vstep = [&](int t, float logit_c) -> int {
        float base = (lane < 32) ? av : xor16f(av, lane);
        float S[16];
        float x;
        S[0] = base + tr2[0];
        ROR(x, base, 1);  S[1]  = x + tr2[1];
        ROR(x, base, 2);  S[2]  = x + tr2[2];
        ROR(x, base, 3);  S[3]  = x + tr2[3];
        ROR(x, base, 4);  S[4]  = x + tr2[4];
        ROR(x, base, 5);  S[5]  = x + tr2[5];
        ROR(x, base, 6);  S[6]  = x + tr2[6];
        ROR(x, base, 7);  S[7]  = x + tr2[7];
        ROR(x, base, 8);  S[8]  = x + tr2[8];
        ROR(x, base, 9);  S[9]  = x + tr2[9];
        ROR(x, base, 10); S[10] = x + tr2[10];
        ROR(x, base, 11); S[11] = x + tr2[11];
        ROR(x, base, 12); S[12] = x + tr2[12];
        ROR(x, base, 13); S[13] = x + tr2[13];
        ROR(x, base, 14); S[14] = x + tr2[14];
        ROR(x, base, 15); S[15] = x + tr2[15];

        float a = fmaxf(fmaxf(S[0], S[1]), S[2]);
        float bq = fmaxf(fmaxf(S[3], S[4]), S[5]);
        float cq = fmaxf(fmaxf(S[6], S[7]), S[8]);
        float dq = fmaxf(fmaxf(S[9], S[10]), S[11]);
        float eq = fmaxf(fmaxf(S[12], S[13]), S[14]);
        float best = fmaxf(fmaxf(fmaxf(a, bq), fmaxf(cq, dq)),
                           fmaxf(eq, S[15]));

        // value recurrence: does NOT wait for the tie-break index
        float ov = xor32f(best, lane);
        av = logit_c + fmaxf(best, ov);

        // tie-break (min prev-tag among maxima) — off the serial chain
        int t8[16];
#pragma unroll
        for (int kk = 0; kk < 16; ++kk)
          t8[kk] = (S[kk] == best) ? pidx[kk] : 63;
        int ma = min(min(t8[0], t8[1]), t8[2]);
        int mb = min(min(t8[3], t8[4]), t8[5]);
        int mc = min(min(t8[6], t8[7]), t8[8]);
        int md = min(min(t8[9], t8[10]), t8[11]);
        int me = min(min(t8[12], t8[13]), t8[14]);
        int bi = min(min(min(ma, mb), min(mc, md)), min(me, t8[15]));

        int oi = xor32i(bi, lane);
        bool take = (ov > best) || (ov == best && oi < bi);
        int bpi = take ? oi : bi;

        // cyclic 4-row backpointer (head-of-backtrace only); both halves
        // write the same value to the same address (free 2-way)
        bp_s[((t - 1) & 3) * CC + c] = (unsigned char)bpi;
        return bpi;
      };

      // immediate (stalling) compose of the pending group — rare paths only
      auto flushPend = [&]() {
        if (pend_tt > 0) {
          int m2 = __builtin_amdgcn_ds_bpermute(p3 << 2, p2);
          int m3 = __builtin_amdgcn_ds_bpermute(m2 << 2, p1);
          int m4 = __builtin_amdgcn_ds_bpermute(m3 << 2, p0);
          gp_s[((pend_tt >> 2) - 1) * CC + c] =
              (unsigned)p3 | ((unsigned)m2 << 8) |
              ((unsigned)m3 << 16) | ((unsigned)m4 << 24);
          pend_tt = 0;
        }
      };

      // first group of a sequence: no pending compose to interleave
      auto groupFirst = [&](float (&bk)[8], int off, int tg) {
        int b0 = vstep(tg + 0, bk[off + 0]);
        int b1 = vstep(tg + 1, bk[off + 1]);
        int b2 = vstep(tg + 2, bk[off + 2]);
        int b3 = vstep(tg + 3, bk[off + 3]);
        p0 = b0; p1 = b1; p2 = b2; p3 = b3; pend_tt = tg + 3;
      };
      // steady state: pipeline pend's compose across this group's 4 vsteps
      auto group = [&](float (&bk)[8], int off, int tg) {
        int m2 = __builtin_amdgcn_ds_bpermute(p3 << 2, p2);
        int b0 = vstep(tg + 0, bk[off + 0]);
        int m3 = __builtin_amdgcn_ds_bpermute(m2 << 2, p1);
        int b1 = vstep(tg + 1, bk[off + 1]);
        int m4 = __builtin_amdgcn_ds_bpermute(m3 << 2, p0);
        int b2 = vstep(tg + 2, bk[off + 2]);
        gp_s[((pend_tt >> 2) - 1) * CC + c] =
            (unsigned)p3 | ((unsigned)m2 << 8) |
            ((unsigned)m3 << 16) | ((unsigned)m4 << 24);
        int b3 = vstep(tg + 3, bk[off + 3]);
        p0 = b0; p1 = b1; p2 = b2; p3 = b3; pend_tt = tg + 3;
      };

      float Abk[8], Bbk[8];
      auto loadC = [&](float (&bk)[8], int t0) {   // clamped, off-chain
#pragma unroll
        for (int s = 0; s < 8; ++s) {
          int tt = t0 + s; tt = tt < len ? tt : len - 1;
          bk[s] = lgc[tt * CC];
        }
      };
      auto guardRun = [&](float (&bk)[8], int tb) {
        int h1 = p3, h2 = p2, h3 = p1;   // recent history from last group
#pragma unroll
        for (int s = 0; s < 8; ++s) {
          int tt = tb + s;
          if (tt < len) {
            int bpi = vstep(tt, bk[s]);
            if ((tt & 3) == 0) {
              flushPend();
              p0 = h3; p1 = h2; p2 = h1; p3 = bpi; pend_tt = tt;
            }
            h3 = h2; h2 = h1; h1 = bpi;
          }
        }
      };

      loadC(Abk, 1);
      int t0 = 1;
      bool first = true;
      for (; t0 + 16 <= len; t0 += 16) {
        loadC(Bbk, t0 + 8);
        if (first) { groupFirst(Abk, 0, t0); first = false; }
        else       { group(Abk, 0, t0); }
        group(Abk, 4, t0 + 4);
        loadC(Abk, t0 + 16);
        group(Bbk, 0, t0 + 8);
        group(Bbk, 4, t0 + 12);
      }
      if (t0 < len) {
        loadC(Bbk, t0 + 8);
        guardRun(Abk, t0);
        if (t0 + 8 < len) guardRun(Bbk, t0 + 8);
      }
      flushPend();

      // last tag: argmax over c (first index on ties)
      float v = av; int idx = c;
#pragma unroll
      for (int d = 1; d < 32; d <<= 1) {
        float v2 = __shfl_xor(v, d, 32);
        int   i2 = __shfl_xor(idx, d, 32);
        if (v2 > v || (v2 == v && i2 < idx)) { v = v2; idx = i2; }
      }

      // backtrace: ragged head via cyclic rows (<=3 steps), then 4-jumps
      if (lane == 0) {
        int tag = idx;
        int t = len - 1;
        tag_s[t] = (unsigned char)tag;
        while (t > 0 && (t & 3) != 0) {
          tag = bp_s[((t - 1) & 3) * CC + tag];
          --t;
          tag_s[t] = (unsigned char)tag;
        }
        while (t >= 4) {
          unsigned u = gp_s[((t >> 2) - 1) * CC + tag];
          tag_s[t - 1] = (unsigned char)(u & 255);
          tag_s[t - 2] = (unsigned char)((u >> 8) & 255);
          tag_s[t - 3] = (unsigned char)((u >> 16) & 255);
          tag = (int)(u >> 24);
          tag_s[t - 4] = (unsigned char)tag;
          t -= 4;
        }
      }

      // coalesced tag store (+ zero padding)
#pragma unroll
      for (int j = 0; j < 8; ++j) {
        int tt = lane + 64 * j;
        float val = (tt < len) ? (float)tag_s[tt] : 0.0f;
        out[bT + tt] = val;
      }
    }

  } else {
    // ================= Forward wave (scaled linear domain) =================
    float E[16];
#pragma unroll
    for (int kk = 0; kk < 16; ++kk) {
      int p = pr * 16 + ((i - kk) & 15);
      E[kk] = EXP2F(trans[p * CC + c] * LOG2E);
    }

    float loss_acc = 0.0f;

    for (int sq = 0; sq < 2; ++sq) {
      const int b = sq ? bs1 : bs0;
      if (b < 0) break;
      const int len = seqlen[b];
      const float* lg = logits + (size_t)b * TT * CC;
      const int* lab = labels + (size_t)b * TT;
      const float* lgc = lg + c;

      float P   = EXP2F(lg[c] * LOG2E);  // scaled linear alpha for column c
      float Acc = 0.0f;                  // accumulated log2 scale (uniform)

      auto fstep = [&](float raw_logit) {
        float el = EXP2F(raw_logit * LOG2E);   // off the serial P-chain
        float base = (lane < 32) ? P : xor16f(P, lane);
        float x;
        float a0 = base * E[0];
        ROR(x, base, 1);  float a1 = x * E[1];
        ROR(x, base, 2);  float a2 = x * E[2];
        ROR(x, base, 3);  float a3 = x * E[3];
        ROR(x, base, 4);  a0 = fmaf(x, E[4],  a0);
        ROR(x, base, 5);  a1 = fmaf(x, E[5],  a1);
        ROR(x, base, 6);  a2 = fmaf(x, E[6],  a2);
        ROR(x, base, 7);  a3 = fmaf(x, E[7],  a3);
        ROR(x, base, 8);  a0 = fmaf(x, E[8],  a0);
        ROR(x, base, 9);  a1 = fmaf(x, E[9],  a1);
        ROR(x, base, 10); a2 = fmaf(x, E[10], a2);
        ROR(x, base, 11); a3 = fmaf(x, E[11], a3);
        ROR(x, base, 12); a0 = fmaf(x, E[12], a0);
        ROR(x, base, 13); a1 = fmaf(x, E[13], a1);
        ROR(x, base, 14); a2 = fmaf(x, E[14], a2);
        ROR(x, base, 15); a3 = fmaf(x, E[15], a3);
        float part = (a0 + a1) + (a2 + a3);      // this lane's 16-row partial
        float oth  = xor32f(part, lane);         // other row's partial
        P = el * (part + oth);
      };

      auto renorm = [&]() {
        float m = P, y;
        ROR(y, m, 8); m = fmaxf(m, y);
        ROR(y, m, 4); m = fmaxf(m, y);
        ROR(y, m, 2); m = fmaxf(m, y);
        ROR(y, m, 1); m = fmaxf(m, y);
        m = fmaxf(m, xor16f(m, lane));
        int e = (int)(__float_as_uint(m) >> 23) - 127;  // floor(log2 m)
        P = ldexpf(P, -e);                              // exact scaling
        Acc += (float)e;
      };

      float Abk[8], Bbk[8];
      auto loadC = [&](float (&bk)[8], int t0) {
#pragma unroll
        for (int s = 0; s < 8; ++s) {
          int tt = t0 + s; tt = tt < len ? tt : len - 1;
          bk[s] = lgc[tt * CC];
        }
      };
      auto runFull = [&](float (&bk)[8]) {     // renorm at static s=3, s=7
        fstep(bk[0]); fstep(bk[1]); fstep(bk[2]); fstep(bk[3]); renorm();
        fstep(bk[4]); fstep(bk[5]); fstep(bk[6]); fstep(bk[7]); renorm();
      };
      auto runGuard = [&](float (&bk)[8], int t0) {
#pragma unroll
        for (int s = 0; s < 8; ++s) {
          int tt = t0 + s;
          if (tt < len) {
            fstep(bk[s]);
            if ((tt & 3) == 0) renorm();
          }
        }
      };

      loadC(Abk, 1);
      int t0 = 1;
      for (; t0 + 16 <= len; t0 += 16) {
        loadC(Bbk, t0 + 8);
        runFull(Abk);
        loadC(Abk, t0 + 16);
        runFull(Bbk);
      }
      if (t0 < len) {
        loadC(Bbk, t0 + 8);
        runGuard(Abk, t0);
        if (t0 + 8 < len) runGuard(Bbk, t0 + 8);
      }

      // gold-path score (unary + binary), lane-parallel over t
      float uacc = 0.0f, bacc = 0.0f;
#pragma unroll
      for (int j = 0; j < 8; ++j) {
        int tt = lane + 64 * j;
        if (tt < len) {
          int lt = lab[tt];
          uacc += lg[tt * CC + lt];
          if (tt + 1 < len) {
            int ln = lab[tt + 1];
            bacc += trans[lt * CC + ln];
          }
        }
      }
#pragma unroll
      for (int d = 32; d >= 1; d >>= 1) {
        uacc += __shfl_xor(uacc, d);
        bacc += __shfl_xor(bacc, d);
      }

      // log partition: rotate-fold sum of the 32 scaled alphas + scale
      float ss = P, y2;
      ROR(y2, ss, 8); ss += y2;
      ROR(y2, ss, 4); ss += y2;
      ROR(y2, ss, 2); ss += y2;
      ROR(y2, ss, 1); ss += y2;
      ss += xor16f(ss, lane);
      float log_norm = LN2 * (Acc + LOG2F(ss));

      loss_acc += (uacc + bacc - log_norm);
    }

    if (lane == 0) {
      atomicAdd(out + (size_t)BB * TT, loss_acc * (-1.0f / BB));
    }
  }
}

extern "C" void kernel_launch(void* const* d_in, const int* in_sizes, int n_in,
                              void* d_out, int out_size, void* d_ws, size_t ws_size,
                              hipStream_t stream) {
  const float* logits = (const float*)d_in[0];
  const int*   seqlen = (const int*)d_in[1];
  const int*   labels = (const int*)d_in[2];
  const float* trans  = (const float*)d_in[3];
  float* out = (float*)d_out;

  if (d_ws != nullptr && ws_size >= BB * sizeof(int)) {
    int* perm = (int*)d_ws;
    schedule_kernel<<<1, TT, 0, stream>>>(seqlen, perm, out);
    crf_kernel<<<dim3(BB / 2), dim3(128), 0, stream>>>(
        logits, seqlen, labels, trans, out, perm);
  } else {
    zero_loss_kernel<<<1, 64, 0, stream>>>(out);
    crf_kernel<<<dim3(BB), dim3(128), 0, stream>>>(
        logits, seqlen, labels, trans, out, nullptr);
  }
}